// Round 8
// baseline (392.288 us; speedup 1.0000x reference)
//
#include <hip/hip_runtime.h>
#include <hip/hip_bf16.h>

typedef __attribute__((ext_vector_type(8))) short short8;
typedef __attribute__((ext_vector_type(4))) float f32x4;
typedef __attribute__((ext_vector_type(16))) float f32x16;

#define O 144
#define NB 32
#define GT 256
#define NPAIRS 10440   // 144*145/2
#define TP 128         // pairs per rn_main block
#define NT 82          // ceil(10440/128)
#define GRID (NB*NT)   // 2624 = 8 * 328

// workspace byte offsets
#define WS_WT   0u          // 3 * 256*256 bf16, (et,ks)-panel layout
#define WS_U    393216u     // 32*144*256 bf16 (u + wq + gb0 folded)
#define WS_V    2752512u    // 32*144*256 bf16
#define WS_REL  5144576u    // 32*256 f32
#define WS_CNT  5177344u    // 32 ints

__device__ __forceinline__ unsigned short f2bf(float f){
  unsigned int uu = __builtin_bit_cast(unsigned int, f);
  unsigned int lsb = (uu >> 16) & 1u;
  uu += 0x7fffu + lsb;               // round-to-nearest-even
  return (unsigned short)(uu >> 16);
}
// HW packed f32->bf16 (RNE), 2 elements in 1 instr
__device__ __forceinline__ unsigned int cvtpk(float lo, float hi){
  unsigned int r;
  asm("v_cvt_pk_bf16_f32 %0, %1, %2" : "=v"(r) : "v"(lo), "v"(hi));
  return r;
}

// ---- merged prep ----
// blocks [0,256): u/v build (n = blk>>3, o-range 18 per block); q-dot once/thread
// blocks [256,1024): Wt panels; first 32 also zero rel; first block zeros cnt
__global__ void prep_all(const float* __restrict__ x, const float* __restrict__ q,
                         const float* __restrict__ gW0, const float* __restrict__ gb0,
                         const float* __restrict__ gW1, const float* __restrict__ gW2,
                         const float* __restrict__ gW3,
                         unsigned short* __restrict__ u, unsigned short* __restrict__ v,
                         unsigned short* __restrict__ WtP, float* __restrict__ rel,
                         int* __restrict__ cnt){
  int blk = blockIdx.x, t = threadIdx.x;
  if (blk < 256){
    __shared__ float xs[24][18];
    __shared__ float qs[128];
    int n = blk >> 3, oq = blk & 7;
    int o0 = oq * 18;
    for (int i = t; i < 432; i += 256){
      int c = i / 18, oo = i - c*18;
      xs[c][oo] = x[(n*24 + c)*144 + o0 + oo];
    }
    if (t < 128) qs[t] = q[n*128 + t];
    __syncthreads();
    float wq = gb0[t];
    for (int d = 0; d < 128; d++) wq += qs[d] * gW0[(52 + d)*GT + t];
    float wc[52];
    #pragma unroll
    for (int c = 0; c < 52; c++) wc[c] = gW0[c*GT + t];
    for (int oo = 0; oo < 18; oo++){
      int o = o0 + oo;
      float xc = -1.f + 2.f * (float)(o / 12) / 11.f;
      float yc = -1.f + 2.f * (float)(o % 12) / 11.f;
      float su = wq + xc*wc[24] + yc*wc[25];
      float sv =      xc*wc[50] + yc*wc[51];
      #pragma unroll
      for (int c = 0; c < 24; c++){ float f = xs[c][oo]; su += f*wc[c]; sv += f*wc[26+c]; }
      u[(size_t)(n*O + o)*GT + t] = f2bf(su);
      v[(size_t)(n*O + o)*GT + t] = f2bf(sv);
    }
  } else {
    int b2 = blk - 256;                // 0..767
    int li = b2 >> 8, e = b2 & 255;
    int k = t;
    const float* W = (li == 0) ? gW1 : (li == 1) ? gW2 : gW3;
    // panel: [li][e>>5][k>>4][ (e&31)*16 + ((k>>3)&1)*8 + (k&7) ]
    WtP[li*65536 + (e>>5)*8192 + (k>>4)*512 + (e&31)*16 + ((k>>3)&1)*8 + (k&7)]
        = f2bf(W[k*GT + e]);
    if (b2 < NB) rel[b2*GT + t] = 0.f;
    if (b2 == 0 && t < NB) cnt[t] = 0;
  }
}

// ---- main fused kernel: 32x32x16 MFMA, B double-buffer, fused f_phi tail ----
// LDS h layout: h[row][col] bf16 at byte  row*512 + ((col*2) ^ ((row&7)<<4))
__global__ __launch_bounds__(256, 2) void rn_main(
    const unsigned short* __restrict__ u, const unsigned short* __restrict__ v,
    const unsigned short* __restrict__ WtP,
    const float* __restrict__ gb1, const float* __restrict__ gb2,
    const float* __restrict__ gb3, float* __restrict__ rel, int* __restrict__ cnt,
    const float* __restrict__ fW0, const float* __restrict__ fb0,
    const float* __restrict__ fW1, const float* __restrict__ fb1,
    const float* __restrict__ fW2, const float* __restrict__ fb2,
    float* __restrict__ out)
{
  __shared__ short8 hbuf[4096];        // 128 rows x 512B, swizzled; exactly 64 KiB
  char* lds = (char*)hbuf;

  const int tid  = threadIdx.x;
  const int lane = tid & 63;
  const int wav  = tid >> 6;           // owns feats [wav*64, +64)
  // XCD-bijective swizzle: 2624 = 8*328 -> each XCD gets 4 consecutive batches
  int lg = (blockIdx.x & 7)*328 + (blockIdx.x >> 3);
  const int n    = lg / NT;
  const int tile = lg - n*NT;
  const int tbase = tile * TP;
  const int l31 = lane & 31, l32 = lane >> 5;

  // A prefetch: phase p = L*16 + ks in [0,48); 2 feat-panels (et) per wave
  const unsigned short* wb = WtP + wav*16384 + l31*16 + l32*8;
  short8 a0n, a1n;
#define LOADA(p_) { const unsigned short* _wp = wb + ((p_) >> 4)*65536 + ((p_) & 15)*512; \
    a0n = *(const short8*)(_wp); a1n = *(const short8*)(_wp + 8192); }
  LOADA(0);

  // ---- stage h0 = relu(u'[n,b] + v[n,a]); 2 lanes per row ----
  {
    int row = wav*32 + (lane >> 1);
    int pt  = tbase + row;
    bool valid = pt < NPAIRS;
    int pa = 0, pb = 0;
    if (valid){
      pa = (int)((sqrtf(8.f*(float)pt + 1.f) - 1.f) * 0.5f);
      while ((pa + 1)*(pa + 2)/2 <= pt) pa++;
      while (pa*(pa + 1)/2 > pt) pa--;
      pb = pt - pa*(pa + 1)/2;
    }
    const uint4* up4 = (const uint4*)(u + (size_t)(n*O + pb)*GT);
    const uint4* vp4 = (const uint4*)(v + (size_t)(n*O + pa)*GT);
    int half = lane & 1;
    int sbase = row*512 + half*256;
    int ts = ((lane >> 1) & 7) << 4;   // (row&7)<<4
    #pragma unroll
    for (int cc = 0; cc < 16; cc++){
      uint4 hv;
      if (valid){
        uint4 uu = up4[half*16 + cc];
        uint4 vv = vp4[half*16 + cc];
        #pragma unroll
        for (int j = 0; j < 4; j++){
          unsigned int ud = (&uu.x)[j], vd = (&vv.x)[j];
          float lo = __builtin_bit_cast(float, ud << 16) + __builtin_bit_cast(float, vd << 16);
          float hi = __builtin_bit_cast(float, ud & 0xffff0000u) + __builtin_bit_cast(float, vd & 0xffff0000u);
          (&hv.x)[j] = cvtpk(fmaxf(lo, 0.f), fmaxf(hi, 0.f));
        }
      } else {
        hv = (uint4){0u, 0u, 0u, 0u};
      }
      *(uint4*)(lds + sbase + ((cc*16) ^ ts)) = hv;
    }
  }
  __syncthreads();

  const bool fullvalid = (tbase + TP <= NPAIRS);
  const int l13 = (lane >> 1) & 3;
  const int l03 = lane & 3;
  const int l2b = (lane >> 2) & 1;
  // B-read base per (ks&3): addr = rb[ks&3] + (ks>>2)*128 + jp*16384
  int rb[4];
  #pragma unroll
  for (int m = 0; m < 4; m++)
    rb[m] = l31*512 + ((m ^ l13) << 5) + ((l32 << 4) ^ ((lane & 1) << 4));
  const int eb = l31*512 + l32*8 + wav*128;   // epilogue base

  f32x16 acc[2][4];
  short8 b0[4], b1[4];
#define LOADB(dst_, ks_) { \
    dst_[0] = *(short8*)(lds + rb[(ks_) & 3] + (((ks_) >> 2)*128)); \
    dst_[1] = *(short8*)(lds + rb[(ks_) & 3] + (((ks_) >> 2)*128 + 16384)); \
    dst_[2] = *(short8*)(lds + rb[(ks_) & 3] + (((ks_) >> 2)*128 + 32768)); \
    dst_[3] = *(short8*)(lds + rb[(ks_) & 3] + (((ks_) >> 2)*128 + 49152)); }

  #pragma unroll
  for (int L = 0; L < 3; L++){
    const float* gb = (L == 0) ? gb1 : (L == 1) ? gb2 : gb3;

    // bias init: reg r of (et,jp) holds feat = wav*64+et*32+(r&3)+8*(r>>2)+4*l32
    #pragma unroll
    for (int et = 0; et < 2; et++){
      #pragma unroll
      for (int qq = 0; qq < 4; qq++){
        f32x4 bb = *(const f32x4*)(gb + wav*64 + et*32 + qq*8 + l32*4);
        #pragma unroll
        for (int rr = 0; rr < 4; rr++){
          #pragma unroll
          for (int jp = 0; jp < 4; jp++) acc[et][jp][qq*4 + rr] = bb[rr];
        }
      }
    }

    LOADB(b0, 0);
    #pragma unroll
    for (int ks = 0; ks < 16; ks++){
      short8 a0 = a0n, a1 = a1n;
      int pn = L*16 + ks + 1; if (pn > 47) pn = 47;
      LOADA(pn);
      if (ks < 15){
        if (ks & 1) { LOADB(b0, ks + 1); } else { LOADB(b1, ks + 1); }
      }
      __builtin_amdgcn_s_setprio(1);
      if ((ks & 1) == 0){
        #pragma unroll
        for (int jp = 0; jp < 4; jp++){
          acc[0][jp] = __builtin_amdgcn_mfma_f32_32x32x16_bf16(a0, b0[jp], acc[0][jp], 0, 0, 0);
          acc[1][jp] = __builtin_amdgcn_mfma_f32_32x32x16_bf16(a1, b0[jp], acc[1][jp], 0, 0, 0);
        }
      } else {
        #pragma unroll
        for (int jp = 0; jp < 4; jp++){
          acc[0][jp] = __builtin_amdgcn_mfma_f32_32x32x16_bf16(a0, b1[jp], acc[0][jp], 0, 0, 0);
          acc[1][jp] = __builtin_amdgcn_mfma_f32_32x32x16_bf16(a1, b1[jp], acc[1][jp], 0, 0, 0);
        }
      }
      __builtin_amdgcn_s_setprio(0);
    }

    if (L < 2){
      __syncthreads();                 // all waves done reading h_in
      #pragma unroll
      for (int et = 0; et < 2; et++){
        #pragma unroll
        for (int qq = 0; qq < 4; qq++){
          int ea = eb + (((qq ^ l03) << 4) | ((et ^ l2b) << 6));
          #pragma unroll
          for (int jp = 0; jp < 4; jp++){
            uint2 w;
            w.x = cvtpk(fmaxf(acc[et][jp][qq*4+0], 0.f), fmaxf(acc[et][jp][qq*4+1], 0.f));
            w.y = cvtpk(fmaxf(acc[et][jp][qq*4+2], 0.f), fmaxf(acc[et][jp][qq*4+3], 0.f));
            *(uint2*)(lds + ea + jp*16384) = w;
          }
        }
      }
      __syncthreads();                 // h_out visible
    } else {
      // layer 3: relu, mask invalid pairs, sum over pairs -> atomics into rel
      #pragma unroll
      for (int et = 0; et < 2; et++){
        f32x16 s;
        #pragma unroll
        for (int r = 0; r < 16; r++) s[r] = 0.f;
        #pragma unroll
        for (int jp = 0; jp < 4; jp++){
          bool pv = fullvalid || (tbase + jp*32 + l31 < NPAIRS);
          #pragma unroll
          for (int r = 0; r < 16; r++){
            float hv = fmaxf(acc[et][jp][r], 0.f);
            s[r] += pv ? hv : 0.f;
          }
        }
        #pragma unroll
        for (int st = 1; st < 32; st <<= 1){
          #pragma unroll
          for (int r = 0; r < 16; r++)
            s[r] += __shfl_xor(s[r], st);
        }
        if (l31 == 0){
          #pragma unroll
          for (int r = 0; r < 16; r++)
            atomicAdd(&rel[n*GT + wav*64 + et*32 + (r&3) + 8*(r>>2) + 4*l32], s[r]);
        }
      }
    }
  }
#undef LOADA
#undef LOADB

  // ---- completion count; last block of batch n runs f_phi ----
  __threadfence();
  __syncthreads();                     // all LDS use above complete
  if (tid == 0) ((int*)lds)[0] = atomicAdd(&cnt[n], 1);
  __syncthreads();
  int done = ((int*)lds)[0];
  __syncthreads();
  if (done == NT - 1){
    __threadfence();
    float* hsm = (float*)lds;
    float* ysm = hsm + 256;
    int t = tid;
    float rv = atomicAdd(&rel[n*GT + t], 0.f);   // coherent read across XCDs
    __syncthreads();                             // lds[0] consumed by all
    hsm[t] = rv;
    __syncthreads();
    float s = fb0[t];
    for (int k = 0; k < 256; k++) s += hsm[k] * fW0[k*GT + t];
    ysm[t] = fmaxf(s, 0.f);
    __syncthreads();
    s = fb1[t];
    for (int k = 0; k < 256; k++) s += ysm[k] * fW1[k*GT + t];
    __syncthreads();
    hsm[t] = fmaxf(s, 0.f);
    __syncthreads();
    if (t < 28){
      s = fb2[t];
      for (int k = 0; k < 256; k++) s += hsm[k] * fW2[k*28 + t];
      out[n*28 + t] = s;
    }
  }
}

extern "C" void kernel_launch(void* const* d_in, const int* in_sizes, int n_in,
                              void* d_out, int out_size, void* d_ws, size_t ws_size,
                              hipStream_t stream){
  (void)in_sizes; (void)n_in; (void)out_size; (void)ws_size;
  const float* x   = (const float*)d_in[0];
  const float* q   = (const float*)d_in[1];
  const float* gW0 = (const float*)d_in[2];
  const float* gb0 = (const float*)d_in[3];
  const float* gW1 = (const float*)d_in[4];
  const float* gb1 = (const float*)d_in[5];
  const float* gW2 = (const float*)d_in[6];
  const float* gb2 = (const float*)d_in[7];
  const float* gW3 = (const float*)d_in[8];
  const float* gb3 = (const float*)d_in[9];
  const float* fW0 = (const float*)d_in[10];
  const float* fb0 = (const float*)d_in[11];
  const float* fW1 = (const float*)d_in[12];
  const float* fb1 = (const float*)d_in[13];
  const float* fW2 = (const float*)d_in[14];
  const float* fb2 = (const float*)d_in[15];

  char* ws = (char*)d_ws;
  unsigned short* WtP = (unsigned short*)(ws + WS_WT);
  unsigned short* u   = (unsigned short*)(ws + WS_U);
  unsigned short* v   = (unsigned short*)(ws + WS_V);
  float* rel = (float*)(ws + WS_REL);
  int*   cnt = (int*)(ws + WS_CNT);
  float* out = (float*)d_out;

  hipLaunchKernelGGL(prep_all, dim3(1024), dim3(256), 0, stream,
                     x, q, gW0, gb0, gW1, gW2, gW3, u, v, WtP, rel, cnt);
  hipLaunchKernelGGL(rn_main, dim3(GRID), dim3(256), 0, stream,
                     u, v, WtP, gb1, gb2, gb3, rel, cnt,
                     fW0, fb0, fW1, fb1, fW2, fb2, out);
}

// Round 9
// 241.671 us; speedup vs baseline: 1.6232x; 1.6232x over previous
//
#include <hip/hip_runtime.h>
#include <hip/hip_bf16.h>

typedef __attribute__((ext_vector_type(8))) short short8;
typedef __attribute__((ext_vector_type(4))) float f32x4;

#define O 144
#define NB 32
#define GT 256
#define NPAIRS 10440   // 144*145/2
#define TP 96          // pairs per rn_main block
#define NT 109         // ceil(10440/96)
#define GRID (NB*NT)   // 3488 = 8 * 436
#define CHUNK 436      // per-XCD chunk (= 4 batches)

// workspace byte offsets
#define WS_WT   0u          // 3 * 256*256 bf16, k-tiled panel layout (R6 mapping)
#define WS_U    393216u     // 32*144*256 bf16 (u + wq + gb0 folded)
#define WS_V    2752512u    // 32*144*256 bf16
#define WS_REL  5144576u    // 32*256 f32
#define WS_CNT  5177344u    // 32 ints

__device__ __forceinline__ unsigned short f2bf(float f){
  unsigned int uu = __builtin_bit_cast(unsigned int, f);
  unsigned int lsb = (uu >> 16) & 1u;
  uu += 0x7fffu + lsb;               // round-to-nearest-even
  return (unsigned short)(uu >> 16);
}
// HW packed f32->bf16 (RNE), 2 elements in 1 instr
__device__ __forceinline__ unsigned int cvtpk(float lo, float hi){
  unsigned int r;
  asm("v_cvt_pk_bf16_f32 %0, %1, %2" : "=v"(r) : "v"(lo), "v"(hi));
  return r;
}

// ---- merged prep ----
// blocks [0,256): u/v build; blocks [256,1024): Wt panels (R6 mapping) + rel/cnt zero
__global__ void prep_all(const float* __restrict__ x, const float* __restrict__ q,
                         const float* __restrict__ gW0, const float* __restrict__ gb0,
                         const float* __restrict__ gW1, const float* __restrict__ gW2,
                         const float* __restrict__ gW3,
                         unsigned short* __restrict__ u, unsigned short* __restrict__ v,
                         unsigned short* __restrict__ WtP, float* __restrict__ rel,
                         int* __restrict__ cnt){
  int blk = blockIdx.x, t = threadIdx.x;
  if (blk < 256){
    __shared__ float xs[24][18];
    __shared__ float qs[128];
    int n = blk >> 3, oq = blk & 7;
    int o0 = oq * 18;
    for (int i = t; i < 432; i += 256){
      int c = i / 18, oo = i - c*18;
      xs[c][oo] = x[(n*24 + c)*144 + o0 + oo];
    }
    if (t < 128) qs[t] = q[n*128 + t];
    __syncthreads();
    float wq = gb0[t];
    for (int d = 0; d < 128; d++) wq += qs[d] * gW0[(52 + d)*GT + t];
    float wc[52];
    #pragma unroll
    for (int c = 0; c < 52; c++) wc[c] = gW0[c*GT + t];
    for (int oo = 0; oo < 18; oo++){
      int o = o0 + oo;
      float xc = -1.f + 2.f * (float)(o / 12) / 11.f;
      float yc = -1.f + 2.f * (float)(o % 12) / 11.f;
      float su = wq + xc*wc[24] + yc*wc[25];
      float sv =      xc*wc[50] + yc*wc[51];
      #pragma unroll
      for (int c = 0; c < 24; c++){ float f = xs[c][oo]; su += f*wc[c]; sv += f*wc[26+c]; }
      u[(size_t)(n*O + o)*GT + t] = f2bf(su);
      v[(size_t)(n*O + o)*GT + t] = f2bf(sv);
    }
  } else {
    int b2 = blk - 256;                // 0..767
    int li = b2 >> 8, e = b2 & 255;
    int k = t;
    const float* W = (li == 0) ? gW1 : (li == 1) ? gW2 : gW3;
    // R6 panel: [li][ (e>>4)*4096 + (k>>5)*512 + (e&15)*32 + ((k>>3)&3)*8 + (k&7) ]
    int et = e >> 4, r = e & 15;
    int kk = k >> 5, g = (k >> 3) & 3, d = k & 7;
    WtP[li*65536 + et*4096 + kk*512 + r*32 + g*8 + d] = f2bf(W[k*GT + e]);
    if (b2 < NB) rel[b2*GT + t] = 0.f;
    if (b2 == 0 && t < NB) cnt[t] = 0;
  }
}

// ---- main fused kernel: 16x16x32 MFMA, 3-deep A-rotation, fused f_phi tail ----
// LDS h layout: h[row][col] bf16 at byte  row*512 + ((col*2) ^ ((row&7)<<4)), 96 rows
__global__ __launch_bounds__(256, 2) void rn_main(
    const unsigned short* __restrict__ u, const unsigned short* __restrict__ v,
    const unsigned short* __restrict__ WtP,
    const float* __restrict__ gb1, const float* __restrict__ gb2,
    const float* __restrict__ gb3, float* __restrict__ rel, int* __restrict__ cnt,
    const float* __restrict__ fW0, const float* __restrict__ fb0,
    const float* __restrict__ fW1, const float* __restrict__ fb1,
    const float* __restrict__ fW2, const float* __restrict__ fb2,
    float* __restrict__ out)
{
  __shared__ short8 hbuf[3072];        // 96 rows x 512B = 48 KiB
  char* lds = (char*)hbuf;

  const int tid  = threadIdx.x;
  const int lane = tid & 63;
  const int wav  = tid >> 6;           // owns feats [wav*64, +64)
  int lg = (blockIdx.x & 7)*CHUNK + (blockIdx.x >> 3);   // bijective XCD swizzle
  const int n    = lg / NT;
  const int tile = lg - n*NT;
  const int tbase = tile * TP;
  const int l15 = lane & 15, l4 = lane >> 4;

  // A-prefetch: phase p = L*8+kk in [0,24); 3-deep named-set rotation
  const unsigned short* wb = WtP + wav*16384 + l15*32 + l4*8;
  short8 aA0,aA1,aA2,aA3, aB0,aB1,aB2,aB3, aC0,aC1,aC2,aC3;
#define LA(s0,s1,s2,s3,p_) { const unsigned short* _wp = wb + ((p_) >> 3)*65536 + ((p_) & 7)*512; \
    s0 = *(const short8*)(_wp);        s1 = *(const short8*)(_wp + 4096); \
    s2 = *(const short8*)(_wp + 8192); s3 = *(const short8*)(_wp + 12288); }
  LA(aA0,aA1,aA2,aA3, 0)
  LA(aB0,aB1,aB2,aB3, 1)
  LA(aC0,aC1,aC2,aC3, 2)

  // ---- stage h0 = relu(u'[n,b] + v[n,a]); 2 lanes per row, rows 0..95 ----
  if (tid < 192){
    int row = tid >> 1;
    int pt  = tbase + row;
    bool valid = pt < NPAIRS;
    int pa = 0, pb = 0;
    if (valid){
      pa = (int)((sqrtf(8.f*(float)pt + 1.f) - 1.f) * 0.5f);
      while ((pa + 1)*(pa + 2)/2 <= pt) pa++;
      while (pa*(pa + 1)/2 > pt) pa--;
      pb = pt - pa*(pa + 1)/2;
    }
    const uint4* up4 = (const uint4*)(u + (size_t)(n*O + pb)*GT);
    const uint4* vp4 = (const uint4*)(v + (size_t)(n*O + pa)*GT);
    int half = tid & 1;
    int sbase = row*512 + half*256;
    int ts = (row & 7) << 4;
    #pragma unroll
    for (int cc = 0; cc < 16; cc++){
      uint4 hv;
      if (valid){
        uint4 uu = up4[half*16 + cc];
        uint4 vv = vp4[half*16 + cc];
        #pragma unroll
        for (int j = 0; j < 4; j++){
          unsigned int ud = (&uu.x)[j], vd = (&vv.x)[j];
          float lo = __builtin_bit_cast(float, ud << 16) + __builtin_bit_cast(float, vd << 16);
          float hi = __builtin_bit_cast(float, ud & 0xffff0000u) + __builtin_bit_cast(float, vd & 0xffff0000u);
          (&hv.x)[j] = cvtpk(fmaxf(lo, 0.f), fmaxf(hi, 0.f));
        }
      } else {
        hv = (uint4){0u, 0u, 0u, 0u};
      }
      *(uint4*)(lds + sbase + ((cc*16) ^ ts)) = hv;
    }
  }
  __syncthreads();

  const bool fullvalid = (tbase + TP <= NPAIRS);
  // B-read bases: true byte = jp*8192 + l15*512 + ((kk*64 + l4*16) ^ ((l15&7)<<4))
  const int swz01 = (l15 & 3) << 4;
  const int swz2  = (l15 & 4) << 4;          // 0 or 64
  const int rbE = l15*512 + ((l4*16) ^ swz01) + swz2;   // even kk
  const int rbO = l15*512 + ((l4*16) ^ swz01) - swz2;   // odd kk
  const int ebase = l15*512 + wav*128 + ((l4*8) ^ ((l15 & 1) << 4)) + ((l15 & 6) << 4);
  f32x4 acc[4][6];

#define MFMA16(s0,s1,s2,s3,kk_) { \
    const int rb_ = ((kk_) & 1) ? rbO : rbE; \
    short8 b_[6]; \
    _Pragma("unroll") \
    for (int jp = 0; jp < 6; jp++) b_[jp] = *(short8*)(lds + rb_ + jp*8192 + (kk_)*64); \
    __builtin_amdgcn_s_setprio(1); \
    _Pragma("unroll") \
    for (int jp = 0; jp < 6; jp++){ \
      acc[0][jp] = __builtin_amdgcn_mfma_f32_16x16x32_bf16(s0, b_[jp], acc[0][jp], 0, 0, 0); \
      acc[1][jp] = __builtin_amdgcn_mfma_f32_16x16x32_bf16(s1, b_[jp], acc[1][jp], 0, 0, 0); \
      acc[2][jp] = __builtin_amdgcn_mfma_f32_16x16x32_bf16(s2, b_[jp], acc[2][jp], 0, 0, 0); \
      acc[3][jp] = __builtin_amdgcn_mfma_f32_16x16x32_bf16(s3, b_[jp], acc[3][jp], 0, 0, 0); } \
    __builtin_amdgcn_s_setprio(0); }

  #pragma unroll
  for (int L = 0; L < 3; L++){
    const float* gb = (L == 0) ? gb1 : (L == 1) ? gb2 : gb3;

    // init accumulators with bias (feature e = wav*64 + ie*16 + l4*4 + j)
    #pragma unroll
    for (int ie = 0; ie < 4; ie++){
      f32x4 bbv = *(const f32x4*)(gb + wav*64 + ie*16 + l4*4);
      #pragma unroll
      for (int jp = 0; jp < 6; jp++) acc[ie][jp] = bbv;
    }

    #pragma unroll
    for (int kk = 0; kk < 8; kk++){
      const int p = L*8 + kk;
      const int pn = (p + 3 > 23) ? 23 : p + 3;
      if ((p % 3) == 0)      { MFMA16(aA0,aA1,aA2,aA3,kk) LA(aA0,aA1,aA2,aA3,pn) }
      else if ((p % 3) == 1) { MFMA16(aB0,aB1,aB2,aB3,kk) LA(aB0,aB1,aB2,aB3,pn) }
      else                   { MFMA16(aC0,aC1,aC2,aC3,kk) LA(aC0,aC1,aC2,aC3,pn) }
    }

    if (L < 2){
      __syncthreads();                 // all waves done reading h_in
      #pragma unroll
      for (int ie = 0; ie < 4; ie++){
        int ea = ebase ^ (ie*32);
        #pragma unroll
        for (int jp = 0; jp < 6; jp++){
          uint2 pk;
          pk.x = cvtpk(fmaxf(acc[ie][jp][0], 0.f), fmaxf(acc[ie][jp][1], 0.f));
          pk.y = cvtpk(fmaxf(acc[ie][jp][2], 0.f), fmaxf(acc[ie][jp][3], 0.f));
          *(uint2*)(lds + ea + jp*8192) = pk;
        }
      }
      __syncthreads();                 // h_out visible to all waves
    } else {
      // layer 3: relu, mask tail pairs, sum over pairs -> atomic into rel
      #pragma unroll
      for (int ie = 0; ie < 4; ie++){
        int e0 = wav*64 + ie*16 + l4*4;
        f32x4 s = {0.f, 0.f, 0.f, 0.f};
        #pragma unroll
        for (int jp = 0; jp < 6; jp++){
          bool pv = fullvalid || (tbase + jp*16 + l15 < NPAIRS);
          #pragma unroll
          for (int j = 0; j < 4; j++){
            float hvv = fmaxf(acc[ie][jp][j], 0.f);
            s[j] += pv ? hvv : 0.f;
          }
        }
        #pragma unroll
        for (int st = 1; st < 16; st <<= 1){
          #pragma unroll
          for (int j = 0; j < 4; j++)
            s[j] += __shfl_xor(s[j], st);
        }
        if (l15 == 0){
          #pragma unroll
          for (int j = 0; j < 4; j++)
            atomicAdd(&rel[n*GT + e0 + j], s[j]);
        }
      }
    }
  }
#undef LA
#undef MFMA16

  // ---- completion count; last block of batch n runs f_phi ----
  // __syncthreads drains vmcnt(0): rel atomics complete at coherent point
  // before the cnt flag increments -> no threadfence (avoids L2 writeback).
  __syncthreads();
  if (tid == 0) ((int*)lds)[0] = atomicAdd(&cnt[n], 1);
  __syncthreads();
  int done = ((int*)lds)[0];
  __syncthreads();                     // everyone consumed flag before LDS reuse
  if (done == NT - 1){
    float rv = atomicAdd(&rel[n*GT + tid], 0.f);   // coherent read across XCDs
    float* hsm = (float*)lds;
    float* ysm = hsm + 256;
    int t = tid;
    hsm[t] = rv;
    __syncthreads();
    float s = fb0[t];
    for (int k = 0; k < 256; k++) s += hsm[k] * fW0[k*GT + t];
    ysm[t] = fmaxf(s, 0.f);
    __syncthreads();
    s = fb1[t];
    for (int k = 0; k < 256; k++) s += ysm[k] * fW1[k*GT + t];
    __syncthreads();
    hsm[t] = fmaxf(s, 0.f);
    __syncthreads();
    if (t < 28){
      s = fb2[t];
      for (int k = 0; k < 256; k++) s += hsm[k] * fW2[k*28 + t];
      out[n*28 + t] = s;
    }
  }
}

extern "C" void kernel_launch(void* const* d_in, const int* in_sizes, int n_in,
                              void* d_out, int out_size, void* d_ws, size_t ws_size,
                              hipStream_t stream){
  (void)in_sizes; (void)n_in; (void)out_size; (void)ws_size;
  const float* x   = (const float*)d_in[0];
  const float* q   = (const float*)d_in[1];
  const float* gW0 = (const float*)d_in[2];
  const float* gb0 = (const float*)d_in[3];
  const float* gW1 = (const float*)d_in[4];
  const float* gb1 = (const float*)d_in[5];
  const float* gW2 = (const float*)d_in[6];
  const float* gb2 = (const float*)d_in[7];
  const float* gW3 = (const float*)d_in[8];
  const float* gb3 = (const float*)d_in[9];
  const float* fW0 = (const float*)d_in[10];
  const float* fb0 = (const float*)d_in[11];
  const float* fW1 = (const float*)d_in[12];
  const float* fb1 = (const float*)d_in[13];
  const float* fW2 = (const float*)d_in[14];
  const float* fb2 = (const float*)d_in[15];

  char* ws = (char*)d_ws;
  unsigned short* WtP = (unsigned short*)(ws + WS_WT);
  unsigned short* u   = (unsigned short*)(ws + WS_U);
  unsigned short* v   = (unsigned short*)(ws + WS_V);
  float* rel = (float*)(ws + WS_REL);
  int*   cnt = (int*)(ws + WS_CNT);
  float* out = (float*)d_out;

  hipLaunchKernelGGL(prep_all, dim3(1024), dim3(256), 0, stream,
                     x, q, gW0, gb0, gW1, gW2, gW3, u, v, WtP, rel, cnt);
  hipLaunchKernelGGL(rn_main, dim3(GRID), dim3(256), 0, stream,
                     u, v, WtP, gb1, gb2, gb3, rel, cnt,
                     fW0, fb0, fW1, fb1, fW2, fb2, out);
}

// Round 10
// 241.228 us; speedup vs baseline: 1.6262x; 1.0018x over previous
//
#include <hip/hip_runtime.h>
#include <hip/hip_bf16.h>

typedef __attribute__((ext_vector_type(8))) short short8;
typedef __attribute__((ext_vector_type(4))) float f32x4;

#define O 144
#define NB 32
#define GT 256
#define NPAIRS 10440   // 144*145/2
#define TP 112         // pairs per rn_main block
#define NT 94          // ceil(10440/112)
#define GRID (NB*NT)   // 3008 = 8 * 376
#define CHUNK 376      // per-XCD chunk (= 4 batches)
#define ROWB 528       // LDS row stride: 512+16 -> rows spread across banks

// workspace byte offsets
#define WS_WT   0u          // 3 * 256*256 bf16, k-tiled panel layout (R6 mapping)
#define WS_U    393216u     // 32*144*256 bf16 (u + wq + gb0 folded)
#define WS_V    2752512u    // 32*144*256 bf16
#define WS_REL  5144576u    // 32*256 f32
#define WS_CNT  5177344u    // 32 ints

__device__ __forceinline__ unsigned short f2bf(float f){
  unsigned int uu = __builtin_bit_cast(unsigned int, f);
  unsigned int lsb = (uu >> 16) & 1u;
  uu += 0x7fffu + lsb;               // round-to-nearest-even
  return (unsigned short)(uu >> 16);
}
// HW packed f32->bf16 (RNE), 2 elements in 1 instr
__device__ __forceinline__ unsigned int cvtpk(float lo, float hi){
  unsigned int r;
  asm("v_cvt_pk_bf16_f32 %0, %1, %2" : "=v"(r) : "v"(lo), "v"(hi));
  return r;
}

// ---- merged prep ----
// blocks [0,256): u/v build; blocks [256,1024): Wt panels (R6 mapping) + rel/cnt zero
__global__ void prep_all(const float* __restrict__ x, const float* __restrict__ q,
                         const float* __restrict__ gW0, const float* __restrict__ gb0,
                         const float* __restrict__ gW1, const float* __restrict__ gW2,
                         const float* __restrict__ gW3,
                         unsigned short* __restrict__ u, unsigned short* __restrict__ v,
                         unsigned short* __restrict__ WtP, float* __restrict__ rel,
                         int* __restrict__ cnt){
  int blk = blockIdx.x, t = threadIdx.x;
  if (blk < 256){
    __shared__ float xs[24][18];
    __shared__ float qs[128];
    int n = blk >> 3, oq = blk & 7;
    int o0 = oq * 18;
    for (int i = t; i < 432; i += 256){
      int c = i / 18, oo = i - c*18;
      xs[c][oo] = x[(n*24 + c)*144 + o0 + oo];
    }
    if (t < 128) qs[t] = q[n*128 + t];
    __syncthreads();
    float wq = gb0[t];
    for (int d = 0; d < 128; d++) wq += qs[d] * gW0[(52 + d)*GT + t];
    float wc[52];
    #pragma unroll
    for (int c = 0; c < 52; c++) wc[c] = gW0[c*GT + t];
    for (int oo = 0; oo < 18; oo++){
      int o = o0 + oo;
      float xc = -1.f + 2.f * (float)(o / 12) / 11.f;
      float yc = -1.f + 2.f * (float)(o % 12) / 11.f;
      float su = wq + xc*wc[24] + yc*wc[25];
      float sv =      xc*wc[50] + yc*wc[51];
      #pragma unroll
      for (int c = 0; c < 24; c++){ float f = xs[c][oo]; su += f*wc[c]; sv += f*wc[26+c]; }
      u[(size_t)(n*O + o)*GT + t] = f2bf(su);
      v[(size_t)(n*O + o)*GT + t] = f2bf(sv);
    }
  } else {
    int b2 = blk - 256;                // 0..767
    int li = b2 >> 8, e = b2 & 255;
    int k = t;
    const float* W = (li == 0) ? gW1 : (li == 1) ? gW2 : gW3;
    // panel: [li][ (e>>4)*4096 + (k>>5)*512 + (e&15)*32 + ((k>>3)&3)*8 + (k&7) ]
    int et = e >> 4, r = e & 15;
    int kk = k >> 5, g = (k >> 3) & 3, d = k & 7;
    WtP[li*65536 + et*4096 + kk*512 + r*32 + g*8 + d] = f2bf(W[k*GT + e]);
    if (b2 < NB) rel[b2*GT + t] = 0.f;
    if (b2 == 0 && t < NB) cnt[t] = 0;
  }
}

// ---- main fused kernel: 16x16x32 MFMA, 528B row stride (no swizzle), fused tail ----
// LDS h layout: h[row][col] bf16 at byte  row*528 + col*2   (112 rows, 59136 B)
__global__ __launch_bounds__(256, 2) void rn_main(
    const unsigned short* __restrict__ u, const unsigned short* __restrict__ v,
    const unsigned short* __restrict__ WtP,
    const float* __restrict__ gb1, const float* __restrict__ gb2,
    const float* __restrict__ gb3, float* __restrict__ rel, int* __restrict__ cnt,
    const float* __restrict__ fW0, const float* __restrict__ fb0,
    const float* __restrict__ fW1, const float* __restrict__ fb1,
    const float* __restrict__ fW2, const float* __restrict__ fb2,
    float* __restrict__ out)
{
  __shared__ char lds[TP*ROWB];        // 59,136 B

  const int tid  = threadIdx.x;
  const int lane = tid & 63;
  const int wav  = tid >> 6;           // owns feats [wav*64, +64)
  int lg = (blockIdx.x & 7)*CHUNK + (blockIdx.x >> 3);   // bijective XCD swizzle
  const int n    = lg / NT;
  const int tile = lg - n*NT;
  const int tbase = tile * TP;
  const int l15 = lane & 15, l4 = lane >> 4;

  // A-prefetch: phase p = L*8+kk in [0,24); 3-deep named-set rotation
  const unsigned short* wb = WtP + wav*16384 + l15*32 + l4*8;
  short8 aA0,aA1,aA2,aA3, aB0,aB1,aB2,aB3, aC0,aC1,aC2,aC3;
#define LA(s0,s1,s2,s3,p_) { const unsigned short* _wp = wb + ((p_) >> 3)*65536 + ((p_) & 7)*512; \
    s0 = *(const short8*)(_wp);        s1 = *(const short8*)(_wp + 4096); \
    s2 = *(const short8*)(_wp + 8192); s3 = *(const short8*)(_wp + 12288); }
  LA(aA0,aA1,aA2,aA3, 0)
  LA(aB0,aB1,aB2,aB3, 1)
  LA(aC0,aC1,aC2,aC3, 2)

  // ---- stage h0 = relu(u'[n,b] + v[n,a]); 2 lanes per row, rows 0..111 ----
  if (tid < 2*TP){
    int row = tid >> 1;
    int pt  = tbase + row;
    bool valid = pt < NPAIRS;
    int pa = 0, pb = 0;
    if (valid){
      pa = (int)((sqrtf(8.f*(float)pt + 1.f) - 1.f) * 0.5f);
      while ((pa + 1)*(pa + 2)/2 <= pt) pa++;
      while (pa*(pa + 1)/2 > pt) pa--;
      pb = pt - pa*(pa + 1)/2;
    }
    const uint4* up4 = (const uint4*)(u + (size_t)(n*O + pb)*GT);
    const uint4* vp4 = (const uint4*)(v + (size_t)(n*O + pa)*GT);
    int half = tid & 1;
    int sbase = row*ROWB + half*256;
    #pragma unroll
    for (int cc = 0; cc < 16; cc++){
      uint4 hv;
      if (valid){
        uint4 uu = up4[half*16 + cc];
        uint4 vv = vp4[half*16 + cc];
        #pragma unroll
        for (int j = 0; j < 4; j++){
          unsigned int ud = (&uu.x)[j], vd = (&vv.x)[j];
          float lo = __builtin_bit_cast(float, ud << 16) + __builtin_bit_cast(float, vd << 16);
          float hi = __builtin_bit_cast(float, ud & 0xffff0000u) + __builtin_bit_cast(float, vd & 0xffff0000u);
          (&hv.x)[j] = cvtpk(fmaxf(lo, 0.f), fmaxf(hi, 0.f));
        }
      } else {
        hv = (uint4){0u, 0u, 0u, 0u};
      }
      *(uint4*)(lds + sbase + cc*16) = hv;
    }
  }
  __syncthreads();

  const bool fullvalid = (tbase + TP <= NPAIRS);
  // B-read: byte = jp*16*ROWB + l15*ROWB + kk*64 + l4*16  (pure immediates per jp,kk)
  const int rbase = l15*ROWB + l4*16;
  // epilogue: byte = (jp*16+l15)*ROWB + wav*128 + ie*32 + l4*8
  const int ebase = l15*ROWB + wav*128 + l4*8;
  f32x4 acc[4][7];

#define MFMA16(s0,s1,s2,s3,kk_) { \
    short8 b_[7]; \
    _Pragma("unroll") \
    for (int jp = 0; jp < 7; jp++) b_[jp] = *(short8*)(lds + rbase + jp*(16*ROWB) + (kk_)*64); \
    __builtin_amdgcn_s_setprio(1); \
    _Pragma("unroll") \
    for (int jp = 0; jp < 7; jp++){ \
      acc[0][jp] = __builtin_amdgcn_mfma_f32_16x16x32_bf16(s0, b_[jp], acc[0][jp], 0, 0, 0); \
      acc[1][jp] = __builtin_amdgcn_mfma_f32_16x16x32_bf16(s1, b_[jp], acc[1][jp], 0, 0, 0); \
      acc[2][jp] = __builtin_amdgcn_mfma_f32_16x16x32_bf16(s2, b_[jp], acc[2][jp], 0, 0, 0); \
      acc[3][jp] = __builtin_amdgcn_mfma_f32_16x16x32_bf16(s3, b_[jp], acc[3][jp], 0, 0, 0); } \
    __builtin_amdgcn_s_setprio(0); }

  #pragma unroll
  for (int L = 0; L < 3; L++){
    const float* gb = (L == 0) ? gb1 : (L == 1) ? gb2 : gb3;

    // init accumulators with bias (feature e = wav*64 + ie*16 + l4*4 + j)
    #pragma unroll
    for (int ie = 0; ie < 4; ie++){
      f32x4 bbv = *(const f32x4*)(gb + wav*64 + ie*16 + l4*4);
      #pragma unroll
      for (int jp = 0; jp < 7; jp++) acc[ie][jp] = bbv;
    }

    #pragma unroll
    for (int kk = 0; kk < 8; kk++){
      const int p = L*8 + kk;
      const int pn = (p + 3 > 23) ? 23 : p + 3;
      if ((p % 3) == 0)      { MFMA16(aA0,aA1,aA2,aA3,kk) LA(aA0,aA1,aA2,aA3,pn) }
      else if ((p % 3) == 1) { MFMA16(aB0,aB1,aB2,aB3,kk) LA(aB0,aB1,aB2,aB3,pn) }
      else                   { MFMA16(aC0,aC1,aC2,aC3,kk) LA(aC0,aC1,aC2,aC3,pn) }
    }

    if (L < 2){
      __syncthreads();                 // all waves done reading h_in
      #pragma unroll
      for (int ie = 0; ie < 4; ie++){
        #pragma unroll
        for (int jp = 0; jp < 7; jp++){
          uint2 pk;
          pk.x = cvtpk(fmaxf(acc[ie][jp][0], 0.f), fmaxf(acc[ie][jp][1], 0.f));
          pk.y = cvtpk(fmaxf(acc[ie][jp][2], 0.f), fmaxf(acc[ie][jp][3], 0.f));
          *(uint2*)(lds + ebase + ie*32 + jp*(16*ROWB)) = pk;
        }
      }
      __syncthreads();                 // h_out visible to all waves
    } else {
      // layer 3: relu, mask tail pairs, sum over pairs -> atomic into rel
      #pragma unroll
      for (int ie = 0; ie < 4; ie++){
        int e0 = wav*64 + ie*16 + l4*4;
        f32x4 s = {0.f, 0.f, 0.f, 0.f};
        #pragma unroll
        for (int jp = 0; jp < 7; jp++){
          bool pv = fullvalid || (tbase + jp*16 + l15 < NPAIRS);
          #pragma unroll
          for (int j = 0; j < 4; j++){
            float hvv = fmaxf(acc[ie][jp][j], 0.f);
            s[j] += pv ? hvv : 0.f;
          }
        }
        #pragma unroll
        for (int st = 1; st < 16; st <<= 1){
          #pragma unroll
          for (int j = 0; j < 4; j++)
            s[j] += __shfl_xor(s[j], st);
        }
        if (l15 == 0){
          #pragma unroll
          for (int j = 0; j < 4; j++)
            atomicAdd(&rel[n*GT + e0 + j], s[j]);
        }
      }
    }
  }
#undef LA
#undef MFMA16

  // ---- completion count; last block of batch n runs f_phi ----
  // __syncthreads drains each wave's outstanding atomics (vmcnt 0) before
  // the flag increments -> no threadfence needed.
  __syncthreads();
  if (tid == 0) ((int*)lds)[0] = atomicAdd(&cnt[n], 1);
  __syncthreads();
  int done = ((int*)lds)[0];
  __syncthreads();                     // everyone consumed flag before LDS reuse
  if (done == NT - 1){
    float rv = atomicAdd(&rel[n*GT + tid], 0.f);   // coherent read across XCDs
    float* hsm = (float*)lds;
    float* ysm = hsm + 256;
    int t = tid;
    hsm[t] = rv;
    __syncthreads();
    float s = fb0[t];
    for (int k = 0; k < 256; k++) s += hsm[k] * fW0[k*GT + t];
    ysm[t] = fmaxf(s, 0.f);
    __syncthreads();
    s = fb1[t];
    for (int k = 0; k < 256; k++) s += ysm[k] * fW1[k*GT + t];
    __syncthreads();
    hsm[t] = fmaxf(s, 0.f);
    __syncthreads();
    if (t < 28){
      s = fb2[t];
      for (int k = 0; k < 256; k++) s += hsm[k] * fW2[k*28 + t];
      out[n*28 + t] = s;
    }
  }
}

extern "C" void kernel_launch(void* const* d_in, const int* in_sizes, int n_in,
                              void* d_out, int out_size, void* d_ws, size_t ws_size,
                              hipStream_t stream){
  (void)in_sizes; (void)n_in; (void)out_size; (void)ws_size;
  const float* x   = (const float*)d_in[0];
  const float* q   = (const float*)d_in[1];
  const float* gW0 = (const float*)d_in[2];
  const float* gb0 = (const float*)d_in[3];
  const float* gW1 = (const float*)d_in[4];
  const float* gb1 = (const float*)d_in[5];
  const float* gW2 = (const float*)d_in[6];
  const float* gb2 = (const float*)d_in[7];
  const float* gW3 = (const float*)d_in[8];
  const float* gb3 = (const float*)d_in[9];
  const float* fW0 = (const float*)d_in[10];
  const float* fb0 = (const float*)d_in[11];
  const float* fW1 = (const float*)d_in[12];
  const float* fb1 = (const float*)d_in[13];
  const float* fW2 = (const float*)d_in[14];
  const float* fb2 = (const float*)d_in[15];

  char* ws = (char*)d_ws;
  unsigned short* WtP = (unsigned short*)(ws + WS_WT);
  unsigned short* u   = (unsigned short*)(ws + WS_U);
  unsigned short* v   = (unsigned short*)(ws + WS_V);
  float* rel = (float*)(ws + WS_REL);
  int*   cnt = (int*)(ws + WS_CNT);
  float* out = (float*)d_out;

  hipLaunchKernelGGL(prep_all, dim3(1024), dim3(256), 0, stream,
                     x, q, gW0, gb0, gW1, gW2, gW3, u, v, WtP, rel, cnt);
  hipLaunchKernelGGL(rn_main, dim3(GRID), dim3(256), 0, stream,
                     u, v, WtP, gb1, gb2, gb3, rel, cnt,
                     fW0, fb0, fW1, fb1, fW2, fb2, out);
}